// Round 4
// baseline (202.800 us; speedup 1.0000x reference)
//
#include <hip/hip_runtime.h>

// SNNLinear, exact-trajectory via integer-digit f16 MFMA. Round 4:
//   - Bt digit planes stored in MFMA-fragment order; GEMM loads B
//     global->VGPR directly (no LDS for B). LDS carries only A (padded).
//   - A LDS row stride padded 32->40 f16 (bank conflicts 8-way -> 2-way).
//
// Math (unchanged, proven R3): Wq = round(W*2^40) split into 4 balanced
// base-2048 digits; f16 MFMA products/f32 accums exact (sums < 2^24);
// int64 recombine -> f64 du -> f32 hi (ss region) + f16 lo*2^12 (ws).
// Scan in f64, identical trajectory to full-f64 R2.
//
// ws: [0, 8MB) Bt digit planes ; [8MB, 21.2MB) lo residual f16.

typedef __attribute__((ext_vector_type(8))) _Float16 half8;
typedef __attribute__((ext_vector_type(4))) _Float16 half4;
typedef __attribute__((ext_vector_type(4))) float f32x4;

#define T_STEPS 100
#define BO 65536
#define K_DIM 1024
#define N_DIM 1024
#define M_ROWS 6400
#define BT_BYTES 8388608          // 16 bn * 32 kt * 16 groups * 512 f16 * 2B
#define LO_OFFSET ((size_t)BT_BYTES)

// ---- decompose W into 4 digit planes, MFMA-fragment-ordered ----
// elem offset in Bt: (((bn*32+kt)*16 + p*4 + n16)*64 + lane)*8 + e
//   n = bn*64 + n16*16 + r16 ; k = kt*32 + quad*8 + e ; lane = quad*16+r16
__global__ __launch_bounds__(256)
void decompose(const float* __restrict__ W, _Float16* __restrict__ Bt) {
    const int id = blockIdx.x * 256 + threadIdx.x;   // 0..131071
    const int n = id >> 7;          // 0..1023
    const int k8 = id & 127;        // 8-element k group
    const float* wp = W + (size_t)n * K_DIM + k8 * 8;
    const float4 w0 = *(const float4*)(wp);
    const float4 w1 = *(const float4*)(wp + 4);
    const float wv[8] = {w0.x, w0.y, w0.z, w0.w, w1.x, w1.y, w1.z, w1.w};
    half8 out[4];
#pragma unroll
    for (int e = 0; e < 8; ++e) {
        long long q = llrint((double)wv[e] * 0x1p40);   // |q| < 2^43
#pragma unroll
        for (int p = 0; p < 3; ++p) {
            const int d = (int)(((q + 1024) & 2047) - 1024);  // [-1024,1023]
            out[p][e] = (_Float16)(float)d;
            q = (q - d) >> 11;                                // exact
        }
        out[3][e] = (_Float16)(float)(int)q;                  // |d3| <= ~707
    }
    const int bn = n >> 6, n16 = (n >> 4) & 3, r16 = n & 15;
    const int kt = k8 >> 2, quad = k8 & 3;
    const int lane = quad * 16 + r16;
    _Float16* base = Bt + (((size_t)bn * 32 + kt) * 16 + n16) * 512 + lane * 8;
#pragma unroll
    for (int p = 0; p < 4; ++p)
        *(half8*)(base + (size_t)p * 2048) = out[p];
}

// ---- GEMM: 128(M)x64(N) block, 4 waves of 64x32, BK=32, 4 digit planes ----
// A via LDS (padded stride 40 f16); B fragments loaded global->VGPR.
__global__ __launch_bounds__(256, 2)
void gemm_mfma(const float* __restrict__ A,      // spikes [M,K] f32 (0/1)
               const _Float16* __restrict__ Bt,  // fragment-ordered digits
               const float* __restrict__ bias,   // [N]
               float* __restrict__ Chi,          // hi part -> ss region
               _Float16* __restrict__ Lo) {      // lo*4096 residual
    __shared__ _Float16 Al[128 * 40];            // stride 40: 2-way banks max
    const int bm = blockIdx.x, bn = blockIdx.y;
    const int tid = threadIdx.x;
    const int lane = tid & 63, wid = tid >> 6;
    const int wm0 = (wid >> 1) * 64;             // wave M origin (0/64)
    const int wn16 = (wid & 1) * 2;              // wave n16 origin (0/2)
    const int quad = lane >> 4, r16 = lane & 15;

    // loop-invariant A fragment pointers
    const half8* ap[4];
#pragma unroll
    for (int i = 0; i < 4; ++i)
        ap[i] = (const half8*)&Al[(wm0 + i * 16 + r16) * 40 + quad * 8];

    f32x4 acc[4][2][4] = {};

    // A staging: 8 threads/row x 16B(f32), rows ar+{0,32,64,96}
    const int ar = tid >> 3;      // 0..31
    const int ac = tid & 7;       // 16B slot within 128B row
    const float* Ag = A + (size_t)(bm * 128) * K_DIM + ac * 4;
    // B fragment base for this thread (chunk-linear, lane-coalesced)
    const _Float16* Bg = Bt + (size_t)bn * 262144 + lane * 8;

    for (int kt = 0; kt < 32; ++kt) {
        float4 av[4];
#pragma unroll
        for (int it = 0; it < 4; ++it)
            av[it] = *(const float4*)(Ag + (size_t)(ar + it * 32) * K_DIM + kt * 32);
        // B fragments for this iter: 8 x b128, direct to registers
        half8 bv[4][2];
        const _Float16* bk = Bg + (size_t)kt * 8192;
#pragma unroll
        for (int p = 0; p < 4; ++p)
#pragma unroll
            for (int j = 0; j < 2; ++j)
                bv[p][j] = *(const half8*)(bk + (size_t)(p * 4 + wn16 + j) * 512);

        __syncthreads();   // previous iter's A-frag reads complete
#pragma unroll
        for (int it = 0; it < 4; ++it) {
            half4 hv;
            hv[0] = (_Float16)av[it].x; hv[1] = (_Float16)av[it].y;
            hv[2] = (_Float16)av[it].z; hv[3] = (_Float16)av[it].w;
            *(half4*)&Al[(ar + it * 32) * 40 + ac * 4] = hv;
        }
        __syncthreads();

        half8 af[4];
#pragma unroll
        for (int i = 0; i < 4; ++i) af[i] = *ap[i];
#pragma unroll
        for (int j = 0; j < 2; ++j)
#pragma unroll
            for (int p = 0; p < 4; ++p) {
                const half8 bf = bv[p][j];
#pragma unroll
                for (int i = 0; i < 4; ++i)
                    acc[i][j][p] = __builtin_amdgcn_mfma_f32_16x16x32_f16(
                        af[i], bf, acc[i][j][p], 0, 0, 0);
            }
    }

    // epilogue: exact int64 recombine -> f64 du -> hi/lo store
#pragma unroll
    for (int i = 0; i < 4; ++i)
#pragma unroll
        for (int j = 0; j < 2; ++j) {
            const int n_g = bn * 64 + (wn16 + j) * 16 + r16;
            const double bv = (double)bias[n_g];
#pragma unroll
            for (int e = 0; e < 4; ++e) {
                long long t = (long long)acc[i][j][3][e];
                t = t * 2048 + (long long)acc[i][j][2][e];
                t = t * 2048 + (long long)acc[i][j][1][e];
                t = t * 2048 + (long long)acc[i][j][0][e];
                const double du = (double)t * 0x1p-40 + bv;
                const float hi = (float)du;
                const float lo = (float)(du - (double)hi);
                const size_t m_g = (size_t)(bm * 128 + wm0 + i * 16 + quad * 4 + e);
                const size_t off = m_g * N_DIM + n_g;
                Chi[off] = hi;
                Lo[off] = (_Float16)(lo * 4096.0f);
            }
        }
}

// ---- membrane scan, f64, in place over ss; 4-deep load prefetch ----
__global__ __launch_bounds__(256)
void snn_scan(float* __restrict__ out, const _Float16* __restrict__ lo,
              const float* __restrict__ mem0) {
    const int bo = blockIdx.x * 256 + threadIdx.x;
    double m = (double)mem0[bo];
    double cnt = 0.0;
    for (int tb = 0; tb < T_STEPS; tb += 4) {
        float h[4], l[4];
#pragma unroll
        for (int u = 0; u < 4; ++u) {
            const size_t idx = (size_t)(tb + u) * BO + bo;
            h[u] = out[idx];
            l[u] = (float)lo[idx];
        }
#pragma unroll
        for (int u = 0; u < 4; ++u) {
            const double du = (double)h[u] + (double)l[u] * 0x1p-12;
            m += du;
            const double s = (m > 15.0) ? 1.0 : 0.0;
            m = fmin(fmax(m, 0.0), 15.0);
            out[(size_t)(tb + u) * BO + bo] = (float)s;
            cnt += s;
            m -= m * s;
        }
    }
    out[(size_t)T_STEPS * BO + bo] = (float)m;
    out[(size_t)(T_STEPS + 1) * BO + bo] = (float)(cnt * 0.01);
}

extern "C" void kernel_launch(void* const* d_in, const int* in_sizes, int n_in,
                              void* d_out, int out_size, void* d_ws, size_t ws_size,
                              hipStream_t stream) {
    const float* spikes = (const float*)d_in[0];  // [100,64,1024]
    const float* mem    = (const float*)d_in[1];  // [64,1024]
    // d_in[2] = hat_spikes: dead in forward
    const float* W      = (const float*)d_in[3];  // [1024,1024]
    const float* b      = (const float*)d_in[4];  // [1024]
    float* out = (float*)d_out;
    _Float16* Bt = (_Float16*)d_ws;
    _Float16* Lo = (_Float16*)((char*)d_ws + LO_OFFSET);

    decompose<<<dim3(512), 256, 0, stream>>>(W, Bt);
    gemm_mfma<<<dim3(50, 16), 256, 0, stream>>>(spikes, Bt, b, out, Lo);
    snn_scan<<<dim3(BO / 256), 256, 0, stream>>>(out, Lo, mem);
}

// Round 5
// 175.295 us; speedup vs baseline: 1.1569x; 1.1569x over previous
//
#include <hip/hip_runtime.h>

// SNNLinear, exact-trajectory via integer-digit f16 MFMA. Round 5:
//   - software-pipelined K-loop: A/B global loads for kt+2 issued before
//     MFMA(kt); ping-pong register buffers; double-buffered LDS for A.
//   - A stored in LDS in MFMA-fragment order -> conflict-free b128 reads.
//   - block 128m x 32n, 4 waves (2m x 2n), wave tile 64x16 -> ~160 VGPR,
//     3 waves/SIMD. Grid (bn fastest) -> per-XCD B-chunk L2 residency.
//
// Math (proven R2/R3/R4, bit-identical): Wq = round(W*2^40), 4 balanced
// base-2048 digit planes; f16 MFMA products/f32 accums exact (< 2^24);
// int64 recombine -> f64 du -> f32 hi (ss region) + f16 lo*2^12 (ws).
// Scan in f64. Outputs: ss[100,64,1024] | mem_out[64,1024] | hat_s[64,1024]
// ws: [0, 8MB) Bt digit planes ; [8MB, 21.2MB) lo residual f16.

typedef __attribute__((ext_vector_type(8))) _Float16 half8;
typedef __attribute__((ext_vector_type(4))) _Float16 half4;
typedef __attribute__((ext_vector_type(4))) float f32x4;

#define T_STEPS 100
#define BO 65536
#define K_DIM 1024
#define BT_BYTES 8388608
#define LO_OFFSET ((size_t)BT_BYTES)

// ---- decompose W into 4 digit planes, MFMA-fragment-ordered (as R4) ----
// elem offset in Bt: (((bn64*32+kt)*16 + p*4 + n16)*512) + lane*8 + e
//   n = bn64*64 + n16*16 + r16 ; k = kt*32 + quad*8 + e ; lane = quad*16+r16
__global__ __launch_bounds__(256)
void decompose(const float* __restrict__ W, _Float16* __restrict__ Bt) {
    const int id = blockIdx.x * 256 + threadIdx.x;   // 0..131071
    const int n = id >> 7;
    const int k8 = id & 127;
    const float* wp = W + (size_t)n * K_DIM + k8 * 8;
    const float4 w0 = *(const float4*)(wp);
    const float4 w1 = *(const float4*)(wp + 4);
    const float wv[8] = {w0.x, w0.y, w0.z, w0.w, w1.x, w1.y, w1.z, w1.w};
    half8 out[4];
#pragma unroll
    for (int e = 0; e < 8; ++e) {
        long long q = llrint((double)wv[e] * 0x1p40);
#pragma unroll
        for (int p = 0; p < 3; ++p) {
            const int d = (int)(((q + 1024) & 2047) - 1024);
            out[p][e] = (_Float16)(float)d;
            q = (q - d) >> 11;
        }
        out[3][e] = (_Float16)(float)(int)q;
    }
    const int bn = n >> 6, n16 = (n >> 4) & 3, r16 = n & 15;
    const int kt = k8 >> 2, quad = k8 & 3;
    const int lane = quad * 16 + r16;
    _Float16* base = Bt + (((size_t)bn * 32 + kt) * 16 + n16) * 512 + lane * 8;
#pragma unroll
    for (int p = 0; p < 4; ++p)
        *(half8*)(base + (size_t)p * 2048) = out[p];
}

// ---- GEMM: block 128m x 32n, BK=32, pipelined ----
__global__ __launch_bounds__(256, 2)
void gemm_mfma(const float* __restrict__ A,      // spikes [M,K] f32 (0/1)
               const _Float16* __restrict__ Bt,  // fragment-ordered digits
               const float* __restrict__ bias,
               float* __restrict__ Chi,
               _Float16* __restrict__ Lo) {
    __shared__ _Float16 Al[2][8192];   // per buf: [mtile 0..7][lane*8+e], frag order
    const int bn = blockIdx.x;         // 0..31 (n / 32)
    const int bm = blockIdx.y;         // 0..49 (m / 128)
    const int tid = threadIdx.x;
    const int lane = tid & 63, wid = tid >> 6;
    const int wm = wid >> 1;           // m half: 0/1
    const int wnj = wid & 1;           // n16 within block's 32
    const int quad = lane >> 4, r16 = lane & 15;
    const int fragsel = (bn & 1) * 2 + wnj;   // n16 index within bn64 chunk

    const int ar = tid >> 3, ac = tid & 7;    // A staging: row, 16B slot
    const float* Ag = A + (size_t)(bm * 128) * K_DIM + ac * 4;
    const _Float16* Bg = Bt + (size_t)(bn >> 1) * 262144
                            + (size_t)fragsel * 512 + lane * 8;

    // LDS write: element (row, k): mt=row>>4, lds = mt*1024 + (quad*16+(row&15))*8 + (k&7)
    const int wbase = ((ac >> 1) * 16 + (ar & 15)) * 8 + (ac & 1) * 4;
    const int mt0 = ar >> 4;                  // rows ar+it*32 -> mt = mt0 + it*2
    const int rbase = wm * 4096 + lane * 8;   // af[i] at rbase + i*1024

    f32x4 acc[4][4] = {};                     // [i][plane]
    float4 av0[4], av1[4];
    half8 bv0[4], bv1[4];
    half8 af[4];

    auto issueA = [&](int kt, float4* av) {
#pragma unroll
        for (int it = 0; it < 4; ++it)
            av[it] = *(const float4*)(Ag + (size_t)(ar + it * 32) * K_DIM + kt * 32);
    };
    auto issueB = [&](int kt, half8* bv) {
        const _Float16* bk = Bg + (size_t)kt * 8192;
#pragma unroll
        for (int p = 0; p < 4; ++p)
            bv[p] = *(const half8*)(bk + p * 2048);
    };
    auto writeA = [&](int buf, const float4* av) {
#pragma unroll
        for (int it = 0; it < 4; ++it) {
            half4 hv;
            hv[0] = (_Float16)av[it].x; hv[1] = (_Float16)av[it].y;
            hv[2] = (_Float16)av[it].z; hv[3] = (_Float16)av[it].w;
            *(half4*)&Al[buf][(mt0 + it * 2) * 1024 + wbase] = hv;
        }
    };
    auto readA = [&](int buf) {
#pragma unroll
        for (int i = 0; i < 4; ++i)
            af[i] = *(const half8*)&Al[buf][rbase + i * 1024];
    };
    auto domfma = [&](const half8* bv) {
#pragma unroll
        for (int p = 0; p < 4; ++p)
#pragma unroll
            for (int i = 0; i < 4; ++i)
                acc[i][p] = __builtin_amdgcn_mfma_f32_16x16x32_f16(
                    af[i], bv[p], acc[i][p], 0, 0, 0);
    };

    // prologue: stage kt=0, prefetch kt=1
    issueA(0, av0);
    issueB(0, bv0);
    issueA(1, av1);
    writeA(0, av0);        // waits av0 only (bv0/av1 stay in flight)
    __syncthreads();
    readA(0);
    issueB(1, bv1);

    for (int kt = 0; kt < 32; kt += 2) {
        // even phase: compute kt (af, bv0); stage kt+1
        if (kt + 2 < 32) issueA(kt + 2, av0);
        domfma(bv0);
        writeA(1, av1);                       // av1 = A(kt+1)
        __syncthreads();
        readA(1);
        if (kt + 2 < 32) issueB(kt + 2, bv0);
        // odd phase: compute kt+1 (af, bv1); stage kt+2
        if (kt + 3 < 32) issueA(kt + 3, av1);
        domfma(bv1);
        if (kt + 2 < 32) {
            writeA(0, av0);                   // av0 = A(kt+2)
            __syncthreads();
            readA(0);
            if (kt + 3 < 32) issueB(kt + 3, bv1);
        }
    }

    // epilogue: exact int64 recombine -> f64 du -> hi/lo store
    const int n_g = bn * 32 + wnj * 16 + r16;
    const double bd = (double)bias[n_g];
#pragma unroll
    for (int i = 0; i < 4; ++i)
#pragma unroll
        for (int e = 0; e < 4; ++e) {
            long long t = (long long)acc[i][3][e];
            t = t * 2048 + (long long)acc[i][2][e];
            t = t * 2048 + (long long)acc[i][1][e];
            t = t * 2048 + (long long)acc[i][0][e];
            const double du = (double)t * 0x1p-40 + bd;
            const float hi = (float)du;
            const float lo_ = (float)(du - (double)hi);
            const size_t m_g = (size_t)(bm * 128 + wm * 64 + i * 16 + quad * 4 + e);
            const size_t off = m_g * 1024 + n_g;
            Chi[off] = hi;
            Lo[off] = (_Float16)(lo_ * 4096.0f);
        }
}

// ---- membrane scan, f64, in place; one-group-ahead prefetch ----
__global__ __launch_bounds__(256)
void snn_scan(float* __restrict__ out, const _Float16* __restrict__ lo,
              const float* __restrict__ mem0) {
    const int bo = blockIdx.x * 256 + threadIdx.x;
    double m = (double)mem0[bo];
    double cnt = 0.0;
    float hA[4], lA[4], hB[4], lB[4];
#pragma unroll
    for (int u = 0; u < 4; ++u) {
        const size_t idx = (size_t)u * BO + bo;
        hA[u] = out[idx];
        lA[u] = (float)lo[idx];
    }
    for (int g = 0; g < 25; ++g) {
        if (g < 24) {
#pragma unroll
            for (int u = 0; u < 4; ++u) {
                const size_t idx = (size_t)((g + 1) * 4 + u) * BO + bo;
                hB[u] = out[idx];
                lB[u] = (float)lo[idx];
            }
        }
#pragma unroll
        for (int u = 0; u < 4; ++u) {
            const double du = (double)hA[u] + (double)lA[u] * 0x1p-12;
            m += du;
            const double s = (m > 15.0) ? 1.0 : 0.0;
            m = fmin(fmax(m, 0.0), 15.0);
            out[(size_t)(g * 4 + u) * BO + bo] = (float)s;
            cnt += s;
            m -= m * s;
        }
#pragma unroll
        for (int u = 0; u < 4; ++u) { hA[u] = hB[u]; lA[u] = lB[u]; }
    }
    out[(size_t)T_STEPS * BO + bo] = (float)m;
    out[(size_t)(T_STEPS + 1) * BO + bo] = (float)(cnt * 0.01);
}

extern "C" void kernel_launch(void* const* d_in, const int* in_sizes, int n_in,
                              void* d_out, int out_size, void* d_ws, size_t ws_size,
                              hipStream_t stream) {
    const float* spikes = (const float*)d_in[0];  // [100,64,1024]
    const float* mem    = (const float*)d_in[1];  // [64,1024]
    // d_in[2] = hat_spikes: dead in forward
    const float* W      = (const float*)d_in[3];  // [1024,1024]
    const float* b      = (const float*)d_in[4];  // [1024]
    float* out = (float*)d_out;
    _Float16* Bt = (_Float16*)d_ws;
    _Float16* Lo = (_Float16*)((char*)d_ws + LO_OFFSET);

    decompose<<<dim3(512), 256, 0, stream>>>(W, Bt);
    gemm_mfma<<<dim3(32, 50), 256, 0, stream>>>(spikes, Bt, b, out, Lo);
    snn_scan<<<dim3(BO / 256), 256, 0, stream>>>(out, Lo, mem);
}

// Round 6
// 158.953 us; speedup vs baseline: 1.2758x; 1.1028x over previous
//
#include <hip/hip_runtime.h>

// SNNLinear, exact-trajectory via integer-digit i8 MFMA. Round 6:
//   - Wq = round(W*2^36) split into 5 balanced base-256 digit planes (i8).
//   - spikes pre-converted to i8 in MFMA A-fragment order (prepass).
//   - GEMM: NO LDS, NO barriers. A and B fragments stream global->VGPR
//     (both pre-tiled in fragment order), ping-pong register pipeline,
//     mfma_i32_16x16x64_i8 accumulates EXACT i32 (|sum| <= 2^17).
//   - int64 Horner recombine -> f64 du -> f32 hi (ss region) + f16 lo*2^12.
//   - scan in f64 (identical math to proven R2), 3-slot rolling prefetch.
//
// Outputs (flat, f32): ss[100,64,1024] | mem_out[64,1024] | hat_s[64,1024]
// ws: [0,6.55M) A8 ; [6.55M,11.8M) Bt ; [11.8M,24.9M) Lo   (<= 26.2M proven)

typedef __attribute__((ext_vector_type(4))) int int4v;

#define T_STEPS 100
#define BO 65536
#define K_DIM 1024
#define A8_OFF 0
#define BT_OFF 6553600
#define LO_OFF 11796480

// ---- prepass: spikes f32 -> i8, A-fragment order ----
// A8[(m16*16 + k64)*1024 + lane*16 + e]; lane = quad*16 + (m&15),
// m16 = m>>4, k64 = k>>6, quad = (k>>4)&3, e = k&15.
__global__ __launch_bounds__(256)
void conv_a(const float* __restrict__ S, signed char* __restrict__ A8) {
    const int id = blockIdx.x * 256 + threadIdx.x;   // 0..409599
    const int m = id >> 6, ks = id & 63;             // ks: 16-k slot
    const float* sp = S + (size_t)m * K_DIM + ks * 16;
    const float4 s0 = *(const float4*)(sp);
    const float4 s1 = *(const float4*)(sp + 4);
    const float4 s2 = *(const float4*)(sp + 8);
    const float4 s3 = *(const float4*)(sp + 12);
    const float sv[16] = {s0.x,s0.y,s0.z,s0.w, s1.x,s1.y,s1.z,s1.w,
                          s2.x,s2.y,s2.z,s2.w, s3.x,s3.y,s3.z,s3.w};
    union { signed char c[16]; int4v v; } u;
#pragma unroll
    for (int e = 0; e < 16; ++e) u.c[e] = (signed char)sv[e];   // exact 0/1
    const size_t off = ((size_t)(m >> 4) * 16 + (ks >> 2)) * 1024
                     + (size_t)((ks & 3) * 16 + (m & 15)) * 16;
    *(int4v*)(A8 + off) = u.v;
}

// ---- prepass: W -> 5 balanced base-256 digit planes, B-fragment order ----
// Bt[((n16g*16 + k64)*5 + p)*1024 + lane*16 + e]; lane = quad*16 + (n&15).
__global__ __launch_bounds__(256)
void decomp_w(const float* __restrict__ W, signed char* __restrict__ Bt) {
    const int id = blockIdx.x * 256 + threadIdx.x;   // 0..65535
    const int n = id >> 6, ks = id & 63;
    const float* wp = W + (size_t)n * K_DIM + ks * 16;
    const float4 w0 = *(const float4*)(wp);
    const float4 w1 = *(const float4*)(wp + 4);
    const float4 w2 = *(const float4*)(wp + 8);
    const float4 w3 = *(const float4*)(wp + 12);
    const float wv[16] = {w0.x,w0.y,w0.z,w0.w, w1.x,w1.y,w1.z,w1.w,
                          w2.x,w2.y,w2.z,w2.w, w3.x,w3.y,w3.z,w3.w};
    union { signed char c[16]; int4v v; } u[5];
#pragma unroll
    for (int e = 0; e < 16; ++e) {
        long long q = llrint((double)wv[e] * 0x1p36);   // |q| < 2^39 (|W|<8)
#pragma unroll
        for (int p = 0; p < 4; ++p) {
            const int d = (int)(((q + 128) & 255) - 128);  // [-128,127]
            u[p].c[e] = (signed char)d;
            q = (q - d) >> 8;                              // exact
        }
        u[4].c[e] = (signed char)q;                        // |d4| <= ~90
    }
    const size_t base = ((size_t)(n >> 4) * 16 + (ks >> 2)) * 5 * 1024
                      + (size_t)((ks & 3) * 16 + (n & 15)) * 16;
#pragma unroll
    for (int p = 0; p < 5; ++p)
        *(int4v*)(Bt + base + (size_t)p * 1024) = u[p].v;
}

// ---- GEMM: block 128m x 32n = 4 waves (2m x 2n), wave 64m x 16n x 5 planes.
// No LDS, no barriers; everything streams global->VGPR in fragment order. ----
__global__ __launch_bounds__(256)
void gemm_i8(const signed char* __restrict__ A8,
             const signed char* __restrict__ Bt,
             const float* __restrict__ bias,
             float* __restrict__ Chi,          // hi -> ss region
             _Float16* __restrict__ Lo) {      // lo*4096 residual
    const int bm = blockIdx.x;                 // 0..49
    const int bn = blockIdx.y;                 // 0..31
    const int tid = threadIdx.x;
    const int lane = tid & 63, wid = tid >> 6;
    const int wm = wid >> 1, wn = wid & 1;
    const int quad = lane >> 4, r16 = lane & 15;
    const int mgb = bm * 8 + wm * 4;           // first m16 group of this wave
    const int ng  = bn * 2 + wn;               // n16 group

    const signed char* Ab = A8 + (size_t)mgb * 16 * 1024 + (size_t)lane * 16;
    const signed char* Bb = Bt + (size_t)ng * 16 * 5 * 1024 + (size_t)lane * 16;

    int4v a0[4], a1[4], b0[5], b1[5];
    int4v acc[4][5] = {};

    auto loadA = [&](int kt, int4v* a) {
#pragma unroll
        for (int i = 0; i < 4; ++i)
            a[i] = *(const int4v*)(Ab + (size_t)(i * 16 + kt) * 1024);
    };
    auto loadB = [&](int kt, int4v* b) {
#pragma unroll
        for (int p = 0; p < 5; ++p)
            b[p] = *(const int4v*)(Bb + (size_t)(kt * 5 + p) * 1024);
    };
    auto mf = [&](const int4v* a, const int4v* b) {
#pragma unroll
        for (int p = 0; p < 5; ++p)
#pragma unroll
            for (int i = 0; i < 4; ++i)
                acc[i][p] = __builtin_amdgcn_mfma_i32_16x16x64_i8(
                    a[i], b[p], acc[i][p], 0, 0, 0);
    };

    loadA(0, a0); loadB(0, b0);      // kt=0 in flight
    loadA(1, a1); loadB(1, b1);      // kt=1 in flight behind it
    for (int kt = 0; kt < 16; kt += 2) {
        mf(a0, b0);                  // waits only the kt slice (vmcnt(9))
        if (kt + 2 < 16) { loadA(kt + 2, a0); loadB(kt + 2, b0); }
        mf(a1, b1);
        if (kt + 3 < 16) { loadA(kt + 3, a1); loadB(kt + 3, b1); }
    }

    // epilogue: exact i64 Horner recombine -> f64 du -> hi/lo store
    const int n_g = bn * 32 + wn * 16 + r16;
    const double bd = (double)bias[n_g];
#pragma unroll
    for (int i = 0; i < 4; ++i)
#pragma unroll
        for (int e = 0; e < 4; ++e) {
            long long t = (long long)acc[i][4][e];
            t = t * 256 + (long long)acc[i][3][e];
            t = t * 256 + (long long)acc[i][2][e];
            t = t * 256 + (long long)acc[i][1][e];
            t = t * 256 + (long long)acc[i][0][e];   // exact, |t| < 2^50
            const double du = (double)t * 0x1p-36 + bd;
            const float hi = (float)du;
            const float lo = (float)(du - (double)hi);
            const size_t m_g = (size_t)(bm * 128 + wm * 64 + i * 16 + quad * 4 + e);
            const size_t off = m_g * 1024 + n_g;
            Chi[off] = hi;
            Lo[off] = (_Float16)(lo * 4096.0f);
        }
}

// ---- membrane scan, f64, in place; 3-slot rolling 2-group-ahead prefetch ----
__global__ __launch_bounds__(256)
void snn_scan(float* __restrict__ out, const _Float16* __restrict__ lo,
              const float* __restrict__ mem0) {
    const int bo = blockIdx.x * 256 + threadIdx.x;
    double m = (double)mem0[bo];
    double cnt = 0.0;
    float h[3][4], l[3][4];
#pragma unroll
    for (int s = 0; s < 2; ++s)
#pragma unroll
        for (int u = 0; u < 4; ++u) {
            const size_t idx = (size_t)(s * 4 + u) * BO + bo;
            h[s][u] = out[idx];
            l[s][u] = (float)lo[idx];
        }
#pragma unroll
    for (int g = 0; g < 25; ++g) {
        const int cs = g % 3, ps = (g + 2) % 3;
        if (g + 2 < 25) {
#pragma unroll
            for (int u = 0; u < 4; ++u) {
                const size_t idx = (size_t)((g + 2) * 4 + u) * BO + bo;
                h[ps][u] = out[idx];
                l[ps][u] = (float)lo[idx];
            }
        }
#pragma unroll
        for (int u = 0; u < 4; ++u) {
            const double du = (double)h[cs][u] + (double)l[cs][u] * 0x1p-12;
            m += du;
            const double s = (m > 15.0) ? 1.0 : 0.0;
            m = fmin(fmax(m, 0.0), 15.0);
            out[(size_t)(g * 4 + u) * BO + bo] = (float)s;
            cnt += s;
            m -= m * s;
        }
    }
    out[(size_t)T_STEPS * BO + bo] = (float)m;
    out[(size_t)(T_STEPS + 1) * BO + bo] = (float)(cnt * 0.01);
}

extern "C" void kernel_launch(void* const* d_in, const int* in_sizes, int n_in,
                              void* d_out, int out_size, void* d_ws, size_t ws_size,
                              hipStream_t stream) {
    const float* spikes = (const float*)d_in[0];  // [100,64,1024]
    const float* mem    = (const float*)d_in[1];  // [64,1024]
    // d_in[2] = hat_spikes: dead in forward
    const float* W      = (const float*)d_in[3];  // [1024,1024]
    const float* b      = (const float*)d_in[4];  // [1024]
    float* out = (float*)d_out;
    signed char* A8 = (signed char*)d_ws + A8_OFF;
    signed char* Bt = (signed char*)d_ws + BT_OFF;
    _Float16*    Lo = (_Float16*)((char*)d_ws + LO_OFF);

    conv_a<<<dim3(1600), 256, 0, stream>>>(spikes, A8);
    decomp_w<<<dim3(256), 256, 0, stream>>>(W, Bt);
    gemm_i8<<<dim3(50, 32), 256, 0, stream>>>(A8, Bt, b, out, Lo);
    snn_scan<<<dim3(BO / 256), 256, 0, stream>>>(out, Lo, mem);
}